// Round 4
// baseline (86.239 us; speedup 1.0000x reference)
//
#include <hip/hip_runtime.h>

#define NAG  8192
#define JCH  128            // j's per block chunk
#define NCH  (NAG / JCH)    // 64 j-chunks
#define IBLK 1024           // i's per block = 256 threads * 4
#define GG   36
#define HID  128

// Per-pair body, 10 VALU, no LDS, no floor, no compares:
//   r' = 2*x_j + (5 - 2*x_i)      (v_fma_f32 with scalar x_j)
//   rc = med3(r', 0, 9.5)          -> trunc == floor, ix' in [0,9]
//   bit = (8*ix' + iy') & 63       (& is free inside v_lshlrev_b64)
// Valid cell (a,b), a=ix'-2, b=iy'-2 in [0,6) -> bit 8a+b+18 (all have
// bit mod 8 >= 2 and bit >= 18). Every invalid (ix',iy') combo lands on
// bit mod 8 in {0,1} or bit < 18 -> never read by kernel 2. Verified
// exhaustively over [0,9]^2.
#define PAIR(QX, QY, BX, BY, M)                                          \
  {                                                                      \
    const float rx = __builtin_amdgcn_fmed3f(                            \
        fmaf(2.0f, (QX), (BX)), 0.0f, 9.5f);                             \
    const float ry = __builtin_amdgcn_fmed3f(                            \
        fmaf(2.0f, (QY), (BY)), 0.0f, 9.5f);                             \
    const int ix = (int)rx;                                              \
    const int iy = (int)ry;                                              \
    const int bp = ((ix << 3) + iy) & 63;                                \
    (M) |= (1ull << bp);                                                 \
  }

#define PAIR_NS(QX, QY, BX, BY, M, J, I)                                 \
  {                                                                      \
    const float rx = __builtin_amdgcn_fmed3f(                            \
        fmaf(2.0f, (QX), (BX)), 0.0f, 9.5f);                             \
    const float ry = __builtin_amdgcn_fmed3f(                            \
        fmaf(2.0f, (QY), (BY)), 0.0f, 9.5f);                             \
    const int ix = (int)rx;                                              \
    const int iy = (int)ry;                                              \
    int bp = ((ix << 3) + iy) & 63;                                      \
    bp = ((J) != (I)) ? bp : 0;     /* bit 0 is dead */                  \
    (M) |= (1ull << bp);                                                 \
  }

// Kernel 1: partial occupancy bitmasks. Grid (8, 64): block = 1024 i's x 128 j's.
// j index is wave-uniform -> obs[j] compiles to scalar loads (s_load), so the
// inner loop is pure VALU + SMEM: no LDS, no syncthreads, no DS pipe.
__global__ __launch_bounds__(256) void occ_pair_masks(
    const float* __restrict__ obs, unsigned long long* __restrict__ partials) {
  const int t  = threadIdx.x;
  const int bx = blockIdx.x, by = blockIdx.y;
  const int i0 = bx * IBLK + t * 4;
  const int jbase = by * JCH;

  const float4* obs4 = (const float4*)obs;
  const float4 A = obs4[i0 / 2];
  const float4 B = obs4[i0 / 2 + 1];
  const float bx0 = 5.0f - A.x * 2.0f, by0 = 5.0f - A.y * 2.0f;
  const float bx1 = 5.0f - A.z * 2.0f, by1 = 5.0f - A.w * 2.0f;
  const float bx2 = 5.0f - B.x * 2.0f, by2 = 5.0f - B.y * 2.0f;
  const float bx3 = 5.0f - B.z * 2.0f, by3 = 5.0f - B.w * 2.0f;

  const float2* obs2 = (const float2*)obs;
  unsigned long long m0 = 0, m1 = 0, m2 = 0, m3 = 0;

  if ((by >> 3) != bx) {            // off-diagonal: no self possible (uniform)
    #pragma unroll 8
    for (int jj = 0; jj < JCH; ++jj) {
      const float2 q = obs2[jbase + jj];   // wave-uniform -> s_load
      PAIR(q.x, q.y, bx0, by0, m0)
      PAIR(q.x, q.y, bx1, by1, m1)
      PAIR(q.x, q.y, bx2, by2, m2)
      PAIR(q.x, q.y, bx3, by3, m3)
    }
  } else {                          // diagonal block: exclude self per pair
    #pragma unroll 8
    for (int jj = 0; jj < JCH; ++jj) {
      const float2 q = obs2[jbase + jj];
      const int j = jbase + jj;
      PAIR_NS(q.x, q.y, bx0, by0, m0, j, i0 + 0)
      PAIR_NS(q.x, q.y, bx1, by1, m1, j, i0 + 1)
      PAIR_NS(q.x, q.y, bx2, by2, m2, j, i0 + 2)
      PAIR_NS(q.x, q.y, bx3, by3, m3, j, i0 + 3)
    }
  }

  unsigned long long* p = partials + (size_t)by * NAG + i0;
  p[0] = m0; p[1] = m1; p[2] = m2; p[3] = m3;
}

// Kernel 2: OR-reduce 64 partials per agent, then out[i] = b + sum_{set cells} W[cell].
// Block = 256 threads = 8 agents x 32 lanes; lane owns 4 consecutive output cols.
__global__ __launch_bounds__(256) void occ_matmul(
    const unsigned long long* __restrict__ partials,
    const float* __restrict__ W, const float* __restrict__ b,
    float* __restrict__ out) {
  const int t     = threadIdx.x;
  const int lane  = t & 31;
  const int agent = blockIdx.x * 8 + (t >> 5);

  unsigned long long m = partials[(size_t)lane * NAG + agent] |
                         partials[(size_t)(lane + 32) * NAG + agent];
  #pragma unroll
  for (int s = 16; s; s >>= 1) m |= __shfl_xor(m, s, 32);

  const unsigned mlo = (unsigned)m;
  const unsigned mhi = (unsigned)(m >> 32);

  const float4* W4 = (const float4*)W;      // 18 KB, L1/L2 resident
  float4 acc = ((const float4*)b)[lane];

  #pragma unroll
  for (int c = 0; c < GG; ++c) {
    const int bit = (c / 6) * 8 + (c % 6) + 18;  // compile-time remap
    const unsigned sel =
        (bit < 32) ? ((mlo >> bit) & 1u) : ((mhi >> (bit - 32)) & 1u);
    const float s = (float)sel;
    const float4 w = W4[c * 32 + lane];
    acc.x = fmaf(s, w.x, acc.x);
    acc.y = fmaf(s, w.y, acc.y);
    acc.z = fmaf(s, w.z, acc.z);
    acc.w = fmaf(s, w.w, acc.w);
  }
  ((float4*)out)[agent * 32 + lane] = acc;
}

extern "C" void kernel_launch(void* const* d_in, const int* in_sizes, int n_in,
                              void* d_out, int out_size, void* d_ws, size_t ws_size,
                              hipStream_t stream) {
  const float* obs = (const float*)d_in[0];   // [8192, 2] f32
  const float* W   = (const float*)d_in[1];   // [36, 128] f32
  const float* b   = (const float*)d_in[2];   // [128] f32
  float* out = (float*)d_out;                 // [8192, 128] f32
  unsigned long long* partials = (unsigned long long*)d_ws;  // 64*8192*8B = 4 MB

  occ_pair_masks<<<dim3(NAG / IBLK, NCH), 256, 0, stream>>>(obs, partials);
  occ_matmul<<<dim3(NAG / 8), 256, 0, stream>>>(partials, W, b, out);
}